// Round 1
// baseline (441.121 us; speedup 1.0000x reference)
//
#include <hip/hip_runtime.h>

// out[b, j] = x[b, j] * fabsf(W[j, j]),  B=65536, D=1024, all fp32.
// Memory-bound: 256 MiB in + 256 MiB out. Vectorized float4, diag staged in LDS.

#define D 1024
#define D4 (D / 4)          // 256 float4 columns
#define BLOCK 256
#define GRID 8192           // 2M threads, 8 float4 iters/thread over 16M float4s

__global__ __launch_bounds__(BLOCK) void diag_scale_kernel(
    const float4* __restrict__ x4,
    const float*  __restrict__ W,
    float4*       __restrict__ out4,
    long long n4) {
  __shared__ float4 ds[D4];  // 4 KiB: |diag(W)| packed as float4 per 4 columns

  const int t = threadIdx.x;
  // Each of the 256 threads loads 4 diagonal elements: W[j*D + j] = W[j*1025].
  {
    const int j = 4 * t;
    float4 dv;
    dv.x = fabsf(W[(long long)(j + 0) * (D + 1)]);
    dv.y = fabsf(W[(long long)(j + 1) * (D + 1)]);
    dv.z = fabsf(W[(long long)(j + 2) * (D + 1)]);
    dv.w = fabsf(W[(long long)(j + 3) * (D + 1)]);
    ds[t] = dv;
  }
  __syncthreads();

  const long long stride = (long long)gridDim.x * blockDim.x;
  for (long long i = (long long)blockIdx.x * blockDim.x + t; i < n4; i += stride) {
    float4 xv = x4[i];
    // Row-major [B, D]: float4 index i covers columns 4*(i%256) .. 4*(i%256)+3.
    const float4 dv = ds[(int)(i & (D4 - 1))];
    xv.x *= dv.x;
    xv.y *= dv.y;
    xv.z *= dv.z;
    xv.w *= dv.w;
    out4[i] = xv;
  }
}

extern "C" void kernel_launch(void* const* d_in, const int* in_sizes, int n_in,
                              void* d_out, int out_size, void* d_ws, size_t ws_size,
                              hipStream_t stream) {
  const float* x = (const float*)d_in[0];
  const float* W = (const float*)d_in[1];
  float* out = (float*)d_out;

  const long long n4 = (long long)out_size / 4;  // 65536*1024/4 = 16,777,216

  diag_scale_kernel<<<GRID, BLOCK, 0, stream>>>(
      (const float4*)x, W, (float4*)out, n4);
}